// Round 1
// baseline (559.397 us; speedup 1.0000x reference)
//
#include <hip/hip_runtime.h>

// MaxUnpooling2D scatter-add.
// Input:  (8,128,128,64) f32, indices int32 in [0, 256*256*64)
// Output: (8,256,256,64) f32, zero-initialized, out[b, idx&~63 | c] += v
//
// Decode simplification (out_c == C == 64):
//   y*(out_w*out_c) + x*out_c + f == (idx & ~63) + c
// where c = input channel (reference substitutes channel pos for idx%64).

constexpr int IN_PER_B_LOG2  = 20;  // 128*128*64 = 2^20
constexpr int OUT_PER_B_LOG2 = 22;  // 256*256*64 = 2^22
constexpr long long N = 8LL << IN_PER_B_LOG2;  // 8,388,608 input elements

__global__ __launch_bounds__(256) void unpool_scatter(
    const float* __restrict__ in,
    const int*   __restrict__ idx,
    float*       __restrict__ out)
{
    int t = blockIdx.x * blockDim.x + threadIdx.x;   // one thread = 4 elements
    float4 v  = reinterpret_cast<const float4*>(in)[t];
    int4   i4 = reinterpret_cast<const int4*>(idx)[t];
    int e0 = t << 2;

    int b = e0 >> IN_PER_B_LOG2;           // same for all 4 (C=64 divides 4-groups)
    int c0 = e0 & 63;                      // channels c0..c0+3, same spatial loc
    int out_b = b << OUT_PER_B_LOG2;

    atomicAdd(out + (out_b | (i4.x & ~63) | (c0 + 0)), v.x);
    atomicAdd(out + (out_b | (i4.y & ~63) | (c0 + 1)), v.y);
    atomicAdd(out + (out_b | (i4.z & ~63) | (c0 + 2)), v.z);
    atomicAdd(out + (out_b | (i4.w & ~63) | (c0 + 3)), v.w);
}

extern "C" void kernel_launch(void* const* d_in, const int* in_sizes, int n_in,
                              void* d_out, int out_size, void* d_ws, size_t ws_size,
                              hipStream_t stream)
{
    const float* in  = (const float*)d_in[0];
    const int*   idx = (const int*)d_in[1];
    float*       out = (float*)d_out;

    // Harness poisons d_out with 0xAA before every call; reference starts from zeros.
    hipMemsetAsync(d_out, 0, (size_t)out_size * sizeof(float), stream);

    const int threads = 256;
    const int n_thr = (int)(N / 4);                 // 2,097,152 threads
    const int blocks = n_thr / threads;             // 8192 blocks
    unpool_scatter<<<blocks, threads, 0, stream>>>(in, idx, out);
}